// Round 8
// baseline (90.303 us; speedup 1.0000x reference)
//
#include <hip/hip_runtime.h>

// R8: MEASUREMENT ROUND. pack identical to R7. gemm body wrapped in an 8x
// idempotent repeat loop (cslot rotated per rep -> same output sum, no CSE;
// memory clobber stops hoisting). Purpose: (1) g = (dur - 20.8)/7 isolates
// per-gemm cost; (2) 8x-long gemm dispatch finally surfaces in rocprof top-5
// with real counters. Tables kept in a region disjoint from reduce scratch.

#define KDIM 4096

typedef __attribute__((ext_vector_type(8)))  short s16x8;
typedef __attribute__((ext_vector_type(4)))  float f32x4;
typedef __attribute__((ext_vector_type(16))) float f32x16;
typedef unsigned short u16;

__device__ __forceinline__ u16 f2bf(float f) {
  unsigned int u = __float_as_uint(f);
  u += 0x7FFF + ((u >> 16) & 1);   // round-to-nearest-even
  return (u16)(u >> 16);
}

// ---- pack x (fp32 256x4096) -> Xp bf16 in 32x32x16-A-fragment order ----
// (byte-identical to R7)
__global__ __launch_bounds__(256) void pack_kernel(const float* __restrict__ x,
                                                   u16* __restrict__ Xp) {
  __shared__ __align__(16) u16 tile[32 * 264];
  const int tid = threadIdx.x;
  const int rg  = blockIdx.x >> 4;
  const int cg  = blockIdx.x & 15;

  #pragma unroll
  for (int i = 0; i < 4; ++i) {
    int g    = i * 2048 + tid * 8;
    int row  = g >> 8;
    int kloc = g & 255;
    const float4* src = (const float4*)(x + (size_t)(rg * 32 + row) * 4096 + cg * 256 + kloc);
    float4 v0 = src[0], v1 = src[1];
    union { u16 u[8]; uint4 v; } o;
    o.u[0] = f2bf(v0.x); o.u[1] = f2bf(v0.y); o.u[2] = f2bf(v0.z); o.u[3] = f2bf(v0.w);
    o.u[4] = f2bf(v1.x); o.u[5] = f2bf(v1.y); o.u[6] = f2bf(v1.z); o.u[7] = f2bf(v1.w);
    *(uint4*)(tile + row * 264 + kloc) = o.v;
  }
  __syncthreads();

  const int lane = tid & 63;
  const int fw   = tid >> 6;
  #pragma unroll
  for (int i = 0; i < 4; ++i) {
    int fidx = i * 4 + fw;
    int cl   = fidx >> 2;
    int kk   = fidx & 3;
    int c    = cg * 4 + cl;
    uint4 v = *(const uint4*)(tile + (lane & 31) * 264 + cl * 64 + kk * 16 + (lane >> 5) * 8);
    size_t u = ((size_t)((c * 8 + rg) * 4 + kk) << 6) + lane;
    *(uint4*)(Xp + (u << 3)) = v;
  }
}

// ---- fused GEMM, 8x repeated for measurement ----
__global__ __launch_bounds__(1024, 4) void gemm_free8(const u16* __restrict__ Xp,
                                                      const float* __restrict__ w,
                                                      float* __restrict__ out) {
  extern __shared__ __align__(16) char pool[];   // 73728 tables + 65536 reduce
  u16*   tab = (u16*)pool;                       // [c][576] u16, survives reps
  float* red = (float*)(pool + 73728);           // 8 slots x 8 KB

  const int tid   = threadIdx.x;
  const int lane  = tid & 63;
  const int wid   = tid >> 6;        // 0..15
  const int half  = wid >> 3;
  const int l31   = lane & 31;
  const int lh    = lane >> 5;
  const int f     = blockIdx.x >> 2;
  const int q     = blockIdx.x & 3;
  const int rg    = q * 2 + half;

  // build all 64 tables once
  const float* wf = w + ((size_t)f << 12);
  #pragma unroll
  for (int j = 0; j < 4; ++j) {
    int c = wid * 4 + j;
    u16 bv = f2bf(wf[(c << 6) + lane]);
    u16* T = tab + c * 576;
    #pragma unroll
    for (int m = 0; m < 8; ++m) {
      int i = (-(lane + m)) & 63;
      T[m * 72 + i] = bv;
    }
  }

  int bofs[4];
  #pragma unroll
  for (int s = 0; s < 4; ++s) {
    int i0 = (lh * 8 - l31 - 16 * s) & 63;
    bofs[s] = (i0 & 7) * 71 + i0;
  }

  __syncthreads();                   // tables visible

  for (int rep = 0; rep < 8; ++rep) {
    asm volatile("" ::: "memory");   // no hoist/CSE across reps
    const int cs = ((wid & 7) + rep) & 7;          // rotated c-slot: same sum
    const u16* abase = Xp + ((size_t)(cs * 8 + rg) * 2048 + lane * 8);

    f32x16 acc0 = {}, acc1 = {};
    s16x8 a0, a1, a2, a3, n0, n1, n2, n3;
    a0 = *(const s16x8*)(abase);
    a1 = *(const s16x8*)(abase + 512);
    a2 = *(const s16x8*)(abase + 1024);
    a3 = *(const s16x8*)(abase + 1536);

    #pragma unroll
    for (int t = 0; t < 8; ++t) {
      if (t < 7) {
        const u16* nb = abase + (size_t)(t + 1) * 131072;
        n0 = *(const s16x8*)(nb);
        n1 = *(const s16x8*)(nb + 512);
        n2 = *(const s16x8*)(nb + 1024);
        n3 = *(const s16x8*)(nb + 1536);
      }
      const u16* T = tab + (8 * t + cs) * 576;
      s16x8 b0 = *(const s16x8*)(T + bofs[0]);
      s16x8 b1 = *(const s16x8*)(T + bofs[1]);
      s16x8 b2 = *(const s16x8*)(T + bofs[2]);
      s16x8 b3 = *(const s16x8*)(T + bofs[3]);
      acc0 = __builtin_amdgcn_mfma_f32_32x32x16_bf16(a0, b0, acc0, 0, 0, 0);
      acc1 = __builtin_amdgcn_mfma_f32_32x32x16_bf16(a0, b2, acc1, 0, 0, 0);
      acc0 = __builtin_amdgcn_mfma_f32_32x32x16_bf16(a1, b3, acc0, 0, 0, 0);
      acc1 = __builtin_amdgcn_mfma_f32_32x32x16_bf16(a1, b1, acc1, 0, 0, 0);
      acc0 = __builtin_amdgcn_mfma_f32_32x32x16_bf16(a2, b2, acc0, 0, 0, 0);
      acc1 = __builtin_amdgcn_mfma_f32_32x32x16_bf16(a2, b0, acc1, 0, 0, 0);
      acc0 = __builtin_amdgcn_mfma_f32_32x32x16_bf16(a3, b1, acc0, 0, 0, 0);
      acc1 = __builtin_amdgcn_mfma_f32_32x32x16_bf16(a3, b3, acc1, 0, 0, 0);
      if (t < 7) { a0 = n0; a1 = n1; a2 = n2; a3 = n3; }
    }

    // epilogue: 8-way cs reduce in red region (disjoint from tables)
    __syncthreads();                 // MFMA-phase readers done; red free

    #define WRITE_ACC(k)                                                      \
      { float* Bf = red + (size_t)(half * 4 + (k)) * 2048;                    \
        _Pragma("unroll")                                                     \
        for (int i = 0; i < 4; ++i) {                                         \
          f32x4 v0 = {acc0[4*i], acc0[4*i+1], acc0[4*i+2], acc0[4*i+3]};      \
          f32x4 v1 = {acc1[4*i], acc1[4*i+1], acc1[4*i+2], acc1[4*i+3]};      \
          *(f32x4*)(Bf + (size_t)i * 256 + lane * 4) = v0;                    \
          *(f32x4*)(Bf + (size_t)(i + 4) * 256 + lane * 4) = v1;              \
        } }
    #define ADD_ACC(k)                                                        \
      { const float* Bf = red + (size_t)(half * 4 + (k)) * 2048;              \
        _Pragma("unroll")                                                     \
        for (int i = 0; i < 4; ++i) {                                         \
          f32x4 v0 = *(const f32x4*)(Bf + (size_t)i * 256 + lane * 4);        \
          f32x4 v1 = *(const f32x4*)(Bf + (size_t)(i + 4) * 256 + lane * 4);  \
          _Pragma("unroll")                                                   \
          for (int e = 0; e < 4; ++e) {                                       \
            acc0[4*i+e] += v0[e];                                             \
            acc1[4*i+e] += v1[e];                                             \
          }                                                                   \
        } }

    if (cs >= 4) WRITE_ACC(cs - 4);
    __syncthreads();
    if (cs < 4) ADD_ACC(cs);
    __syncthreads();
    if (cs == 2 || cs == 3) WRITE_ACC(cs - 2);
    __syncthreads();
    if (cs < 2) ADD_ACC(cs);
    __syncthreads();
    if (cs == 1) WRITE_ACC(0);
    __syncthreads();
    if (cs == 0) {
      ADD_ACC(0);
      const int colg = (f << 6) + l31;
      const int rowb = q * 64 + half * 32 + 4 * lh;
      #pragma unroll
      for (int r = 0; r < 16; ++r) {
        int row = rowb + (r & 3) + 8 * (r >> 2);
        out[(size_t)row * 4096 + colg]      = acc0[r];
        out[(size_t)row * 4096 + colg + 32] = acc1[r];
      }
    }
    __syncthreads();                 // red readers done before next rep writes
  }
}

extern "C" void kernel_launch(void* const* d_in, const int* in_sizes, int n_in,
                              void* d_out, int out_size, void* d_ws, size_t ws_size,
                              hipStream_t stream) {
  const float* x = (const float*)d_in[0];    // (256, 4096) fp32
  const float* w = (const float*)d_in[1];    // (64, 64, 64) fp32
  float* out = (float*)d_out;                // (256, 4096) fp32

  u16* Xp = (u16*)d_ws;                      // 2 MB packed bf16 X

  pack_kernel<<<128, 256, 0, stream>>>(x, Xp);
  gemm_free8<<<256, 1024, 139264, stream>>>(Xp, w, out);
}

// Round 9
// 19.794 us; speedup vs baseline: 4.5622x; 4.5622x over previous
//
#include <hip/hip_runtime.h>

// out[b, f*64+n] = sum_c sum_j x[b, c*64+j] * w[f, c, (n-j)&63]
// R9: latency attack. Depth-2 A-prefetch (3 register sets, no copy-drain),
// flattened 2-barrier epilogue. Structure otherwise = R7: 256 blocks x 1024
// thr (4 waves/SIMD), A-frags streamed from L2 (pre-packed), circulant
// tables in LDS, mfma_f32_32x32x16_bf16.

#define KDIM 4096

typedef __attribute__((ext_vector_type(8)))  short s16x8;
typedef __attribute__((ext_vector_type(4)))  float f32x4;
typedef __attribute__((ext_vector_type(16))) float f32x16;
typedef unsigned short u16;

__device__ __forceinline__ u16 f2bf(float f) {
  unsigned int u = __float_as_uint(f);
  u += 0x7FFF + ((u >> 16) & 1);   // round-to-nearest-even
  return (u16)(u >> 16);
}

// ---- pack x (fp32 256x4096) -> Xp bf16 in 32x32x16-A-fragment order ----
// (byte-identical to R7)
__global__ __launch_bounds__(256) void pack_kernel(const float* __restrict__ x,
                                                   u16* __restrict__ Xp) {
  __shared__ __align__(16) u16 tile[32 * 264];
  const int tid = threadIdx.x;
  const int rg  = blockIdx.x >> 4;
  const int cg  = blockIdx.x & 15;

  #pragma unroll
  for (int i = 0; i < 4; ++i) {
    int g    = i * 2048 + tid * 8;
    int row  = g >> 8;
    int kloc = g & 255;
    const float4* src = (const float4*)(x + (size_t)(rg * 32 + row) * 4096 + cg * 256 + kloc);
    float4 v0 = src[0], v1 = src[1];
    union { u16 u[8]; uint4 v; } o;
    o.u[0] = f2bf(v0.x); o.u[1] = f2bf(v0.y); o.u[2] = f2bf(v0.z); o.u[3] = f2bf(v0.w);
    o.u[4] = f2bf(v1.x); o.u[5] = f2bf(v1.y); o.u[6] = f2bf(v1.z); o.u[7] = f2bf(v1.w);
    *(uint4*)(tile + row * 264 + kloc) = o.v;
  }
  __syncthreads();

  const int lane = tid & 63;
  const int fw   = tid >> 6;
  #pragma unroll
  for (int i = 0; i < 4; ++i) {
    int fidx = i * 4 + fw;
    int cl   = fidx >> 2;
    int kk   = fidx & 3;
    int c    = cg * 4 + cl;
    uint4 v = *(const uint4*)(tile + (lane & 31) * 264 + cl * 64 + kk * 16 + (lane >> 5) * 8);
    size_t u = ((size_t)((c * 8 + rg) * 4 + kk) << 6) + lane;
    *(uint4*)(Xp + (u << 3)) = v;
  }
}

// ---- fused circulant GEMM, depth-2 prefetch ----
__global__ __launch_bounds__(1024, 4) void gemm_p2(const u16* __restrict__ Xp,
                                                   const float* __restrict__ w,
                                                   float* __restrict__ out) {
  extern __shared__ __align__(16) char pool[];   // 131072 B
  u16*   tab = (u16*)pool;                       // [c][576] u16 (73728 B)
  float* red = (float*)pool;                     // epilogue: 16 slots x 8 KB

  const int tid   = threadIdx.x;
  const int lane  = tid & 63;
  const int wid   = tid >> 6;        // 0..15 = half*8 + cslot
  const int cslot = wid & 7;
  const int half  = wid >> 3;
  const int l31   = lane & 31;
  const int lh    = lane >> 5;
  const int f     = blockIdx.x >> 2;
  const int q     = blockIdx.x & 3;
  const int rg    = q * 2 + half;

  // build all 64 circulant tables: wave wid builds c = wid*4 .. wid*4+3
  const float* wf = w + ((size_t)f << 12);
  #pragma unroll
  for (int j = 0; j < 4; ++j) {
    int c = wid * 4 + j;
    u16 bv = f2bf(wf[(c << 6) + lane]);
    u16* T = tab + c * 576;
    #pragma unroll
    for (int m = 0; m < 8; ++m) {
      int i = (-(lane + m)) & 63;
      T[m * 72 + i] = bv;
    }
  }

  int bofs[4];
  #pragma unroll
  for (int s = 0; s < 4; ++s) {
    int i0 = (lh * 8 - l31 - 16 * s) & 63;
    bofs[s] = (i0 & 7) * 71 + i0;    // copy i0&7, 16B-aligned window
  }

  const u16* abase = Xp + ((size_t)(cslot * 8 + rg) * 2048 + lane * 8);

  // depth-2 prefetch: 3 A register sets, rotated by static index (full unroll)
  s16x8 A[3][4];
  #pragma unroll
  for (int kk = 0; kk < 4; ++kk) {
    A[0][kk] = *(const s16x8*)(abase + kk * 512);              // t=0
    A[1][kk] = *(const s16x8*)(abase + 131072 + kk * 512);     // t=1
  }

  f32x16 acc0 = {}, acc1 = {};

  __syncthreads();                   // tables visible

  #pragma unroll
  for (int t = 0; t < 8; ++t) {
    if (t < 6) {                     // issue loads for t+2 into set (t+2)%3
      const u16* nb = abase + (size_t)(t + 2) * 131072;
      #pragma unroll
      for (int kk = 0; kk < 4; ++kk)
        A[(t + 2) % 3][kk] = *(const s16x8*)(nb + kk * 512);
    }
    const u16* T = tab + (8 * t + cslot) * 576;
    s16x8 b0 = *(const s16x8*)(T + bofs[0]);
    s16x8 b1 = *(const s16x8*)(T + bofs[1]);
    s16x8 b2 = *(const s16x8*)(T + bofs[2]);
    s16x8 b3 = *(const s16x8*)(T + bofs[3]);
    const int cu = t % 3;
    acc0 = __builtin_amdgcn_mfma_f32_32x32x16_bf16(A[cu][0], b0, acc0, 0, 0, 0);
    acc1 = __builtin_amdgcn_mfma_f32_32x32x16_bf16(A[cu][0], b2, acc1, 0, 0, 0);
    acc0 = __builtin_amdgcn_mfma_f32_32x32x16_bf16(A[cu][1], b3, acc0, 0, 0, 0);
    acc1 = __builtin_amdgcn_mfma_f32_32x32x16_bf16(A[cu][1], b1, acc1, 0, 0, 0);
    acc0 = __builtin_amdgcn_mfma_f32_32x32x16_bf16(A[cu][2], b2, acc0, 0, 0, 0);
    acc1 = __builtin_amdgcn_mfma_f32_32x32x16_bf16(A[cu][2], b0, acc1, 0, 0, 0);
    acc0 = __builtin_amdgcn_mfma_f32_32x32x16_bf16(A[cu][3], b1, acc0, 0, 0, 0);
    acc1 = __builtin_amdgcn_mfma_f32_32x32x16_bf16(A[cu][3], b3, acc1, 0, 0, 0);
  }

  // ---- flattened epilogue: 2 barriers total ----
  __syncthreads();                   // all table reads done; reuse pool
  {
    float* slot = red + wid * 2048;  // 8 KB per wave
    #pragma unroll
    for (int i = 0; i < 4; ++i) {
      f32x4 v0 = {acc0[4*i], acc0[4*i+1], acc0[4*i+2], acc0[4*i+3]};
      f32x4 v1 = {acc1[4*i], acc1[4*i+1], acc1[4*i+2], acc1[4*i+3]};
      *(f32x4*)(slot + ((i)     * 64 + lane) * 4) = v0;
      *(f32x4*)(slot + ((i + 4) * 64 + lane) * 4) = v1;
    }
  }
  __syncthreads();
  {
    const int rhalf = tid >> 9;          // which half's slots we reduce
    const int ii    = (tid >> 6) & 7;    // 0..3 = acc0 quads, 4..7 = acc1
    const int sl    = tid & 63;          // source lane
    f32x4 s = {};
    #pragma unroll
    for (int cs = 0; cs < 8; ++cs)
      s += *(const f32x4*)(red + (size_t)(rhalf * 8 + cs) * 2048 + (ii * 64 + sl) * 4);
    // writer-lane sl, reg r=4*(ii&3)+e: row = half*32 + 4*(sl>>5) + e + 8*(ii&3)
    const int col  = (f << 6) + (ii >> 2) * 32 + (sl & 31);
    const int rowb = q * 64 + rhalf * 32 + 4 * (sl >> 5) + 8 * (ii & 3);
    #pragma unroll
    for (int e = 0; e < 4; ++e)
      out[(size_t)(rowb + e) * 4096 + col] = s[e];
  }
}

extern "C" void kernel_launch(void* const* d_in, const int* in_sizes, int n_in,
                              void* d_out, int out_size, void* d_ws, size_t ws_size,
                              hipStream_t stream) {
  const float* x = (const float*)d_in[0];    // (256, 4096) fp32
  const float* w = (const float*)d_in[1];    // (64, 64, 64) fp32
  float* out = (float*)d_out;                // (256, 4096) fp32

  u16* Xp = (u16*)d_ws;                      // 2 MB packed bf16 X

  pack_kernel<<<128, 256, 0, stream>>>(x, Xp);
  gemm_p2<<<256, 1024, 131072, stream>>>(Xp, w, out);
}

// Round 10
// 19.072 us; speedup vs baseline: 4.7347x; 1.0378x over previous
//
#include <hip/hip_runtime.h>

// out[b, f*64+n] = sum_c sum_j x[b, c*64+j] * w[f, c, (n-j)&63]
// R10: compiler-proof depth-2 A-prefetch. R8 showed VGPR_Count=64 -> the
// allocator collapsed R9's prefetch arrays back to depth-0 (serialized
// vmcnt-drain per step, ~900cy/step). Fix: named register sets (no arrays),
// 8 hand-unrolled steps with literal set indices, sched_barrier(0) fence
// between load-issue and MFMA cluster each step. Else identical to R9.

#define KDIM 4096

typedef __attribute__((ext_vector_type(8)))  short s16x8;
typedef __attribute__((ext_vector_type(4)))  float f32x4;
typedef __attribute__((ext_vector_type(16))) float f32x16;
typedef unsigned short u16;

__device__ __forceinline__ u16 f2bf(float f) {
  unsigned int u = __float_as_uint(f);
  u += 0x7FFF + ((u >> 16) & 1);   // round-to-nearest-even
  return (u16)(u >> 16);
}

// ---- pack x (fp32 256x4096) -> Xp bf16 in 32x32x16-A-fragment order ----
// (byte-identical to R7)
__global__ __launch_bounds__(256) void pack_kernel(const float* __restrict__ x,
                                                   u16* __restrict__ Xp) {
  __shared__ __align__(16) u16 tile[32 * 264];
  const int tid = threadIdx.x;
  const int rg  = blockIdx.x >> 4;
  const int cg  = blockIdx.x & 15;

  #pragma unroll
  for (int i = 0; i < 4; ++i) {
    int g    = i * 2048 + tid * 8;
    int row  = g >> 8;
    int kloc = g & 255;
    const float4* src = (const float4*)(x + (size_t)(rg * 32 + row) * 4096 + cg * 256 + kloc);
    float4 v0 = src[0], v1 = src[1];
    union { u16 u[8]; uint4 v; } o;
    o.u[0] = f2bf(v0.x); o.u[1] = f2bf(v0.y); o.u[2] = f2bf(v0.z); o.u[3] = f2bf(v0.w);
    o.u[4] = f2bf(v1.x); o.u[5] = f2bf(v1.y); o.u[6] = f2bf(v1.z); o.u[7] = f2bf(v1.w);
    *(uint4*)(tile + row * 264 + kloc) = o.v;
  }
  __syncthreads();

  const int lane = tid & 63;
  const int fw   = tid >> 6;
  #pragma unroll
  for (int i = 0; i < 4; ++i) {
    int fidx = i * 4 + fw;
    int cl   = fidx >> 2;
    int kk   = fidx & 3;
    int c    = cg * 4 + cl;
    uint4 v = *(const uint4*)(tile + (lane & 31) * 264 + cl * 64 + kk * 16 + (lane >> 5) * 8);
    size_t u = ((size_t)((c * 8 + rg) * 4 + kk) << 6) + lane;
    *(uint4*)(Xp + (u << 3)) = v;
  }
}

// ---- fused circulant GEMM, pinned depth-2 prefetch ----
__global__ __launch_bounds__(1024, 4) void gemm_pin(const u16* __restrict__ Xp,
                                                    const float* __restrict__ w,
                                                    float* __restrict__ out) {
  extern __shared__ __align__(16) char pool[];   // 131072 B
  u16*   tab = (u16*)pool;                       // [c][576] u16 (73728 B)
  float* red = (float*)pool;                     // epilogue: 16 slots x 8 KB

  const int tid   = threadIdx.x;
  const int lane  = tid & 63;
  const int wid   = tid >> 6;        // 0..15 = half*8 + cslot
  const int cslot = wid & 7;
  const int half  = wid >> 3;
  const int l31   = lane & 31;
  const int lh    = lane >> 5;
  const int f     = blockIdx.x >> 2;
  const int q     = blockIdx.x & 3;
  const int rg    = q * 2 + half;

  // build all 64 circulant tables: wave wid builds c = wid*4 .. wid*4+3
  const float* wf = w + ((size_t)f << 12);
  #pragma unroll
  for (int j = 0; j < 4; ++j) {
    int c = wid * 4 + j;
    u16 bv = f2bf(wf[(c << 6) + lane]);
    u16* T = tab + c * 576;
    #pragma unroll
    for (int m = 0; m < 8; ++m) {
      int i = (-(lane + m)) & 63;
      T[m * 72 + i] = bv;
    }
  }

  int bofs0, bofs1, bofs2, bofs3;
  {
    int i0;
    i0 = (lh * 8 - l31)      & 63; bofs0 = (i0 & 7) * 71 + i0;
    i0 = (lh * 8 - l31 - 16) & 63; bofs1 = (i0 & 7) * 71 + i0;
    i0 = (lh * 8 - l31 - 32) & 63; bofs2 = (i0 & 7) * 71 + i0;
    i0 = (lh * 8 - l31 - 48) & 63; bofs3 = (i0 & 7) * 71 + i0;
  }

  const u16* abase = Xp + ((size_t)(cslot * 8 + rg) * 2048 + lane * 8);

  // 3 named A register sets (depth-2 prefetch, un-collapsible)
  s16x8 A0_0, A0_1, A0_2, A0_3;
  s16x8 A1_0, A1_1, A1_2, A1_3;
  s16x8 A2_0, A2_1, A2_2, A2_3;

  #define ALOAD(SET, T)                                       \
    { const u16* nb_ = abase + (size_t)(T) * 131072;          \
      A##SET##_0 = *(const s16x8*)(nb_);                      \
      A##SET##_1 = *(const s16x8*)(nb_ + 512);                \
      A##SET##_2 = *(const s16x8*)(nb_ + 1024);               \
      A##SET##_3 = *(const s16x8*)(nb_ + 1536); }

  ALOAD(0, 0)
  ALOAD(1, 1)

  f32x16 acc0 = {}, acc1 = {};

  __syncthreads();                   // tables visible

  // one K-step: optional prefetch of set PRE for c-index T+2, then 4 b-reads,
  // position fence, 8 MFMAs on set CUR. Literal set indices -> static regs.
  #define STEP(T, CUR, PRE, DOPRE)                                            \
    {                                                                         \
      if (DOPRE) ALOAD(PRE, (T) + 2)                                          \
      const u16* Tb = tab + (8 * (T) + cslot) * 576;                          \
      s16x8 b0 = *(const s16x8*)(Tb + bofs0);                                 \
      s16x8 b1 = *(const s16x8*)(Tb + bofs1);                                 \
      s16x8 b2 = *(const s16x8*)(Tb + bofs2);                                 \
      s16x8 b3 = *(const s16x8*)(Tb + bofs3);                                 \
      __builtin_amdgcn_sched_barrier(0);                                      \
      acc0 = __builtin_amdgcn_mfma_f32_32x32x16_bf16(A##CUR##_0, b0, acc0, 0, 0, 0); \
      acc1 = __builtin_amdgcn_mfma_f32_32x32x16_bf16(A##CUR##_0, b2, acc1, 0, 0, 0); \
      acc0 = __builtin_amdgcn_mfma_f32_32x32x16_bf16(A##CUR##_1, b3, acc0, 0, 0, 0); \
      acc1 = __builtin_amdgcn_mfma_f32_32x32x16_bf16(A##CUR##_1, b1, acc1, 0, 0, 0); \
      acc0 = __builtin_amdgcn_mfma_f32_32x32x16_bf16(A##CUR##_2, b2, acc0, 0, 0, 0); \
      acc1 = __builtin_amdgcn_mfma_f32_32x32x16_bf16(A##CUR##_2, b0, acc1, 0, 0, 0); \
      acc0 = __builtin_amdgcn_mfma_f32_32x32x16_bf16(A##CUR##_3, b1, acc0, 0, 0, 0); \
      acc1 = __builtin_amdgcn_mfma_f32_32x32x16_bf16(A##CUR##_3, b3, acc1, 0, 0, 0); \
    }

  STEP(0, 0, 2, 1)
  STEP(1, 1, 0, 1)
  STEP(2, 2, 1, 1)
  STEP(3, 0, 2, 1)
  STEP(4, 1, 0, 1)
  STEP(5, 2, 1, 1)
  STEP(6, 0, 2, 0)
  STEP(7, 1, 2, 0)

  // ---- flattened epilogue: 2 barriers total (identical to R9) ----
  __syncthreads();                   // all table reads done; reuse pool
  {
    float* slot = red + wid * 2048;  // 8 KB per wave
    #pragma unroll
    for (int i = 0; i < 4; ++i) {
      f32x4 v0 = {acc0[4*i], acc0[4*i+1], acc0[4*i+2], acc0[4*i+3]};
      f32x4 v1 = {acc1[4*i], acc1[4*i+1], acc1[4*i+2], acc1[4*i+3]};
      *(f32x4*)(slot + ((i)     * 64 + lane) * 4) = v0;
      *(f32x4*)(slot + ((i + 4) * 64 + lane) * 4) = v1;
    }
  }
  __syncthreads();
  {
    const int rhalf = tid >> 9;          // which half's slots we reduce
    const int ii    = (tid >> 6) & 7;    // 0..3 = acc0 quads, 4..7 = acc1
    const int sl    = tid & 63;          // source lane
    f32x4 s = {};
    #pragma unroll
    for (int cs = 0; cs < 8; ++cs)
      s += *(const f32x4*)(red + (size_t)(rhalf * 8 + cs) * 2048 + (ii * 64 + sl) * 4);
    const int col  = (f << 6) + (ii >> 2) * 32 + (sl & 31);
    const int rowb = q * 64 + rhalf * 32 + 4 * (sl >> 5) + 8 * (ii & 3);
    #pragma unroll
    for (int e = 0; e < 4; ++e)
      out[(size_t)(rowb + e) * 4096 + col] = s[e];
  }
}

extern "C" void kernel_launch(void* const* d_in, const int* in_sizes, int n_in,
                              void* d_out, int out_size, void* d_ws, size_t ws_size,
                              hipStream_t stream) {
  const float* x = (const float*)d_in[0];    // (256, 4096) fp32
  const float* w = (const float*)d_in[1];    // (64, 64, 64) fp32
  float* out = (float*)d_out;                // (256, 4096) fp32

  u16* Xp = (u16*)d_ws;                      // 2 MB packed bf16 X

  pack_kernel<<<128, 256, 0, stream>>>(x, Xp);
  gemm_pin<<<256, 1024, 131072, stream>>>(Xp, w, out);
}